// Round 8
// baseline (146.072 us; speedup 1.0000x reference)
//
#include <hip/hip_runtime.h>
#include <hip/hip_bf16.h>

#define B_ 8
#define T_ 2048
#define E_ 1024
#define D_ 128

typedef __attribute__((ext_vector_type(8))) short short8;
typedef __attribute__((ext_vector_type(4))) short short4v;
typedef __attribute__((ext_vector_type(4))) float floatx4;
typedef __attribute__((ext_vector_type(16))) float floatx16;
typedef __attribute__((ext_vector_type(2))) unsigned int uint2v;

__device__ __forceinline__ unsigned short f2b(float f) {
  union { float f; unsigned int u; } v; v.f = f;
  unsigned int u = v.u;
  return (unsigned short)((u + 0x7fffu + ((u >> 16) & 1u)) >> 16);  // RNE
}

// v_cvt_pk_bf16_f32: lo16 = bf16(a), hi16 = bf16(b), RNE (same as f2b).
__device__ __forceinline__ unsigned int cvtpk_bf16(float a, float b) {
  unsigned int r;
  asm("v_cvt_pk_bf16_f32 %0, %1, %2" : "=v"(r) : "v"(a), "v"(b));
  return r;
}

#if defined(__has_builtin)
#if __has_builtin(__builtin_amdgcn_permlane32_swap)
#define HAVE_PL32 1
#endif
#endif

#if defined(HAVE_PL32)
#define PLSWAP(a, b)                                                         \
  {                                                                          \
    auto _r = __builtin_amdgcn_permlane32_swap((a), (b), false, false);      \
    (a) = (unsigned int)_r[0];                                               \
    (b) = (unsigned int)_r[1];                                               \
  }
#else
#define PLSWAP(a, b)                                                         \
  {                                                                          \
    unsigned int _pa = (unsigned int)__shfl_xor((int)(b), 32, 64);           \
    unsigned int _pb = (unsigned int)__shfl_xor((int)(a), 32, 64);           \
    if (hi) { (a) = _pa; } else { (b) = _pb; }                               \
  }
#endif

__device__ __forceinline__ float xhalf_max(float x) {
#if defined(HAVE_PL32)
  auto r = __builtin_amdgcn_permlane32_swap(__float_as_uint(x), __float_as_uint(x),
                                            false, false);
  return fmaxf(__uint_as_float((unsigned int)r[0]), __uint_as_float((unsigned int)r[1]));
#else
  return fmaxf(x, __uint_as_float((unsigned int)__shfl_xor(
                      (int)__float_as_uint(x), 32, 64)));
#endif
}

__device__ __forceinline__ float xhalf_sum(float x) {
#if defined(HAVE_PL32)
  auto r = __builtin_amdgcn_permlane32_swap(__float_as_uint(x), __float_as_uint(x),
                                            false, false);
  return __uint_as_float((unsigned int)r[0]) + __uint_as_float((unsigned int)r[1]);
#else
  return x + __uint_as_float((unsigned int)__shfl_xor(
                 (int)__float_as_uint(x), 32, 64));
#endif
}

#if defined(__has_builtin)
#if __has_builtin(__builtin_amdgcn_exp2f)
#define EXP2F(x) __builtin_amdgcn_exp2f(x)
#else
#define EXP2F(x) exp2f(x)
#endif
#else
#define EXP2F(x) exp2f(x)
#endif

// ---------------------------------------------------------------------------
// Kernel 1: W [1024x128] fp32 -> Wf frag-packed bf16 via LDS transpose.
// Wf layout: [g][gi=16][kf=2][ng=8][lane=64][8]  (lane = quad*16 + l16,
// element j: k = gi*64 + kf*32 + quad*8 + j, n = ng*16 + l16).
// log2e/sqrt(128) folded into Wq. (verified r11)
// ---------------------------------------------------------------------------
__global__ __launch_bounds__(256) void wtrans_kernel(
    const float* __restrict__ Wq, const float* __restrict__ Wk,
    const float* __restrict__ Wv, unsigned short* __restrict__ Wf) {
  __shared__ __align__(16) unsigned short Tls[32][136];
  const int tid = threadIdx.x;
  const int w = blockIdx.x >> 5;
  const int rem = blockIdx.x & 31;
  const int k0 = (rem >> 2) * 128;
  const int n0 = (rem & 3) * 32;
  const float* W = (w == 0) ? Wq : ((w == 1) ? Wk : Wv);
  const float scale = (w == 0) ? (1.4426950408889634f * 0.08838834764831845f) : 1.0f;
#pragma unroll
  for (int j = 0; j < 4; j++) {
    int id = tid + 256 * j;
    int k = id >> 3;
    int nn = (id & 7) * 4;
    float4 v = *(const float4*)(W + (size_t)(k0 + k) * D_ + n0 + nn);
    Tls[nn + 0][k] = f2b(v.x * scale);
    Tls[nn + 1][k] = f2b(v.y * scale);
    Tls[nn + 2][k] = f2b(v.z * scale);
    Tls[nn + 3][k] = f2b(v.w * scale);
  }
  __syncthreads();
#pragma unroll
  for (int j = 0; j < 2; j++) {
    int id = tid + 256 * j;
    int n = id >> 4;
    int seg = id & 15;
    short8 o = *(const short8*)&Tls[n][seg * 8];
    int gn = n0 + n;          // channel 0..127
    int kk = k0 + seg * 8;    // k 0..1023, 8-aligned
    size_t off = ((((size_t)w * 16 + (kk >> 6)) * 2 + ((kk >> 5) & 1)) * 8 + (gn >> 4)) * 512 +
                 (size_t)(((kk >> 3) & 3) * 16 + (gn & 15)) * 8;
    *(short8*)&Wf[off] = o;
  }
}

// ---------------------------------------------------------------------------
// Kernel 2: fused QKV v3 — ONE block computes Q,K,V for its 32-token slice.
// r14 lesson: xpack prepass cost (~25us streaming + extra launch) ate qkv's
// gain. Now: X fp32 read from HBM exactly ONCE by its owning block; no Xf.
//   - 512 blocks x 256 thr; wave = 32 tok x 96 ch (acc[2][6]); ~130 VGPR ->
//     2 blocks/CU co-resident.
//   - T14 staging: global X loads for stage s+1 issued at iter start, cvt_pk
//     + 1 ds_write_b128 AFTER the 24-MFMA block; 1 barrier/iter.
//   - LDS 2x4KB; X tile stored with bijective idx' = l16*4+quad repack ->
//     stores <=2-way bank conflict, frag reads conflict-free (both sides).
//   - W register-direct from L2-resident Wf (wave's 6 groups span g).
// ---------------------------------------------------------------------------
#define LOADW6(DST, GI)                                                      \
  _Pragma("unroll") for (int nt_ = 0; nt_ < 6; nt_++) {                      \
    const int c16_ = wv * 6 + nt_;                                           \
    const int g_ = c16_ >> 3;                                                 \
    const int ng_ = c16_ & 7;                                                 \
    _Pragma("unroll") for (int kf_ = 0; kf_ < 2; kf_++)                      \
        DST[nt_][kf_] = *(const short8*)(Wf +                                \
            ((((size_t)g_ * 16 + (GI)) * 2 + kf_) * 8 + ng_) * 512 + lane * 8); \
  }

#define XLOAD(XR, S)                                                         \
  {                                                                          \
    const float* src_ = X + (size_t)(m0 + (tid >> 3)) * E_ + (S) * 64 + (tid & 7) * 8; \
    XR[0] = *(const float4*)src_;                                            \
    XR[1] = *(const float4*)(src_ + 4);                                      \
  }

#define XWRITE(XR, BUF)                                                      \
  {                                                                          \
    union { short8 v; unsigned int q[4]; } pk_;                              \
    pk_.q[0] = cvtpk_bf16(XR[0].x, XR[0].y);                                 \
    pk_.q[1] = cvtpk_bf16(XR[0].z, XR[0].w);                                 \
    pk_.q[2] = cvtpk_bf16(XR[1].x, XR[1].y);                                 \
    pk_.q[3] = cvtpk_bf16(XR[1].z, XR[1].w);                                 \
    *(short8*)&Xs[BUF][xdst] = pk_.v;                                        \
  }

#define QCOMPUTE6(CW, BUF)                                                   \
  {                                                                          \
    short8 af[2][2];                                                         \
    _Pragma("unroll") for (int mt = 0; mt < 2; mt++)                         \
      _Pragma("unroll") for (int kf = 0; kf < 2; kf++)                       \
        af[mt][kf] = *(const short8*)&Xs[BUF][((mt * 2 + kf) * 64 + rdix) * 8]; \
    _Pragma("unroll") for (int nt = 0; nt < 6; nt++)                         \
      _Pragma("unroll") for (int kf = 0; kf < 2; kf++) {                     \
        acc[0][nt] = __builtin_amdgcn_mfma_f32_16x16x32_bf16(af[0][kf], CW[nt][kf], acc[0][nt], 0, 0, 0); \
        acc[1][nt] = __builtin_amdgcn_mfma_f32_16x16x32_bf16(af[1][kf], CW[nt][kf], acc[1][nt], 0, 0, 0); \
      }                                                                      \
  }

__global__ __launch_bounds__(256, 2) void qkv_kernel(
    const float* __restrict__ X, const unsigned short* __restrict__ Wf,
    unsigned short* __restrict__ Qf, unsigned short* __restrict__ Kf,
    unsigned short* __restrict__ Vf) {
  __shared__ __align__(16) unsigned short Xs[2][4 * 512];  // 2 x 4 KB
  const int tid = threadIdx.x;
  const int wv = tid >> 6;
  const int lane = tid & 63;
  const int l16 = lane & 15;
  const int quad = lane >> 4;

  const int bloc = blockIdx.x;   // 0..511
  const int m0 = bloc * 32;

  // staging dest (idx' = l16*4 + quad repack; bijective, <=2-way store conf.)
  const int r_s = tid >> 3;            // token row 0..31
  const int ks_s = tid & 7;            // 8-k segment
  const int xdst = (((r_s >> 4) * 2 + (ks_s >> 2)) * 64 + (r_s & 15) * 4 + (ks_s & 3)) * 8;
  // frag read idx' for MFMA lane: (l16*4 + quad)
  const int rdix = l16 * 4 + quad;

  floatx4 acc[2][6];
#pragma unroll
  for (int mt = 0; mt < 2; mt++)
#pragma unroll
    for (int nt = 0; nt < 6; nt++) acc[mt][nt] = (floatx4){0.f, 0.f, 0.f, 0.f};

  float4 xr[2];
  XLOAD(xr, 0);
  XWRITE(xr, 0);
  __syncthreads();

  short8 w6[6][2];
#pragma unroll
  for (int li = 0; li < 16; li++) {
    if (li < 15) XLOAD(xr, li + 1);   // issue early (T14)
    LOADW6(w6, li);
    QCOMPUTE6(w6, li & 1);
    if (li < 15) XWRITE(xr, (li + 1) & 1);  // write late, after compute
    __syncthreads();
  }

  // Epilogue -> fragment-packed outputs. C/D: col(n)=l16, row(m)=quad*4+r.
  // (verified r12 math; g derived per nt since wave spans Q/K/V channels)
#pragma unroll
  for (int mt = 0; mt < 2; mt++)
#pragma unroll
    for (int nt = 0; nt < 6; nt++) {
      int dg = wv * 96 + nt * 16 + l16;  // 0..383
      int g = dg >> 7;
      int d = dg & 127;
      unsigned short* Fg = (g == 0) ? Qf : ((g == 1) ? Kf : Vf);
      int t0 = m0 + mt * 16 + quad * 4;
      int b = t0 >> 11;
      int tt0 = t0 & (T_ - 1);
      int tile = tt0 >> 5;
      if (g < 2) {
        int kf = d >> 4;
        int hi2 = (d >> 3) & 1;
        int j = d & 7;
        int l32b = tt0 & 31;  // + r
        size_t base = ((size_t)((b * 64 + tile) * 8 + kf)) * 512 + hi2 * 256 + j;
#pragma unroll
        for (int r = 0; r < 4; r++)
          Fg[base + (size_t)(l32b + r) * 8] = f2b(acc[mt][nt][r]);
      } else {
        int k2 = (tt0 >> 4) & 1;
        int hi2 = (tt0 >> 3) & 1;
        int jb = tt0 & 7;  // 0 or 4; +r contiguous
        int l32 = d & 31;
        int dt = d >> 5;
        size_t base = ((size_t)((b * 64 + tile) * 8 + k2 * 4 + dt)) * 512 +
                      (size_t)(hi2 * 32 + l32) * 8 + jb;
        uint2v pv;
        pv.x = cvtpk_bf16(acc[mt][nt][0], acc[mt][nt][1]);
        pv.y = cvtpk_bf16(acc[mt][nt][2], acc[mt][nt][3]);
        *(uint2v*)&Fg[base] = pv;
      }
    }
}

// ---------------------------------------------------------------------------
// Kernel 3: causal flash attention — frag-packed register-direct, barrier-free
// K-loop with manual K-prefetch + T13 defer-max + T12 cvt_pk/permlane pack.
// (verified r9 version, unchanged)
// ---------------------------------------------------------------------------
#define LOADK(DST, ITV)                                                      \
  _Pragma("unroll") for (int kf_ = 0; kf_ < 8; kf_++)                        \
      DST[kf_] = *(const short8*)(Kbase + (size_t)(ITV) * 4096 + kf_ * 512 + lane * 8);

#define LOADV(DST, ITV)                                                      \
  _Pragma("unroll") for (int f_ = 0; f_ < 8; f_++)                           \
      DST[f_] = *(const short8*)(Vbase + (size_t)(ITV) * 4096 + f_ * 512 + lane * 8);

#define ATTN_STEP(KFR, VFR, ITV)                                             \
  {                                                                          \
    floatx16 sacc;                                                           \
    _Pragma("unroll") for (int r = 0; r < 16; r++) sacc[r] = 0.f;            \
    _Pragma("unroll") for (int kf = 0; kf < 8; kf++)                         \
        sacc = __builtin_amdgcn_mfma_f32_32x32x16_bf16(KFR[kf], qf[kf], sacc, 0, 0, 0); \
    if ((ITV) == qt) {                                                       \
      _Pragma("unroll") for (int r = 0; r < 16; r++) {                       \
        int kv = (ITV) * 32 + (r & 3) + 8 * (r >> 2) + 4 * hi;               \
        if (kv > qg) sacc[r] = -1e30f;                                       \
      }                                                                      \
    }                                                                        \
    float mx = fmaxf(                                                        \
        fmaxf(fmaxf(fmaxf(sacc[0], sacc[1]), fmaxf(sacc[2], sacc[3])),       \
              fmaxf(fmaxf(sacc[4], sacc[5]), fmaxf(sacc[6], sacc[7]))),      \
        fmaxf(fmaxf(fmaxf(sacc[8], sacc[9]), fmaxf(sacc[10], sacc[11])),     \
              fmaxf(fmaxf(sacc[12], sacc[13]), fmaxf(sacc[14], sacc[15])))); \
    mx = xhalf_max(mx);                                                      \
    float mnew = fmaxf(mval, mx);                                            \
    if (__any((mnew - mval) > 8.f)) {                                        \
      float alpha = EXP2F(mval - mnew);                                      \
      mval = mnew;                                                           \
      lval *= alpha;                                                         \
      _Pragma("unroll") for (int dt = 0; dt < 4; dt++)                       \
          _Pragma("unroll") for (int r = 0; r < 16; r++) oacc[dt][r] *= alpha; \
    }                                                                        \
    _Pragma("unroll") for (int r = 0; r < 16; r++)                           \
        sacc[r] = EXP2F(sacc[r] - mval);                                     \
    lval += (((sacc[0] + sacc[1]) + (sacc[2] + sacc[3])) +                   \
             ((sacc[4] + sacc[5]) + (sacc[6] + sacc[7]))) +                  \
            (((sacc[8] + sacc[9]) + (sacc[10] + sacc[11])) +                 \
             ((sacc[12] + sacc[13]) + (sacc[14] + sacc[15])));               \
    unsigned int c0_ = cvtpk_bf16(sacc[0], sacc[1]);                         \
    unsigned int c1_ = cvtpk_bf16(sacc[2], sacc[3]);                         \
    unsigned int c2_ = cvtpk_bf16(sacc[4], sacc[5]);                         \
    unsigned int c3_ = cvtpk_bf16(sacc[6], sacc[7]);                         \
    unsigned int c4_ = cvtpk_bf16(sacc[8], sacc[9]);                         \
    unsigned int c5_ = cvtpk_bf16(sacc[10], sacc[11]);                       \
    unsigned int c6_ = cvtpk_bf16(sacc[12], sacc[13]);                       \
    unsigned int c7_ = cvtpk_bf16(sacc[14], sacc[15]);                       \
    PLSWAP(c0_, c2_);                                                        \
    PLSWAP(c1_, c3_);                                                        \
    PLSWAP(c4_, c6_);                                                        \
    PLSWAP(c5_, c7_);                                                        \
    union { short8 s; unsigned int u[4]; } pf0, pf1;                         \
    pf0.u[0] = c0_; pf0.u[1] = c1_; pf0.u[2] = c2_; pf0.u[3] = c3_;          \
    pf1.u[0] = c4_; pf1.u[1] = c5_; pf1.u[2] = c6_; pf1.u[3] = c7_;          \
    _Pragma("unroll") for (int dt = 0; dt < 4; dt++) {                       \
      oacc[dt] = __builtin_amdgcn_mfma_f32_32x32x16_bf16(VFR[dt], pf0.s, oacc[dt], 0, 0, 0);     \
      oacc[dt] = __builtin_amdgcn_mfma_f32_32x32x16_bf16(VFR[4 + dt], pf1.s, oacc[dt], 0, 0, 0); \
    }                                                                        \
  }

__global__ __launch_bounds__(256, 2) void attn_kernel(
    const unsigned short* __restrict__ Qf, const unsigned short* __restrict__ Kf,
    const unsigned short* __restrict__ Vf, float* __restrict__ Out) {
  __shared__ float Om[3][128][32];  // 48 KB merge buffer
  __shared__ float Ms[4][32], Ls[4][32];

  const int tid = threadIdx.x;
  const int wv = tid >> 6;
  const int lane = tid & 63;
  const int l32 = lane & 31;
  const int hi = lane >> 5;

  const int batch = blockIdx.x & 7;
  const int qt = 63 - (blockIdx.x >> 3);  // longest-first
  const int qb = qt * 32;
  const int qg = qb + l32;

  const unsigned short* Kbase = Kf + (size_t)batch * 64 * 4096;
  const unsigned short* Vbase = Vf + (size_t)batch * 64 * 4096;

  // Q B-frags: coalesced base+lane*16
  short8 qf[8];
  const unsigned short* Qp = Qf + (size_t)(batch * 64 + qt) * 4096;
#pragma unroll
  for (int kf = 0; kf < 8; kf++)
    qf[kf] = *(const short8*)(Qp + kf * 512 + lane * 8);

  floatx16 oacc[4];  // O^T: col q=l32, row d=dt*32+(r&3)+8*(r>>2)+4*hi
#pragma unroll
  for (int dt = 0; dt < 4; dt++)
#pragma unroll
    for (int r = 0; r < 16; r++) oacc[dt][r] = 0.f;
  float mval = -1e30f, lval = 0.f;

  short8 kA[8], kB[8], vC[8];
  int it = wv;
  if (it <= qt) {
    LOADK(kA, it);
    while (true) {
      int nit = it + 4;
      LOADV(vC, it);
      if (nit <= qt) LOADK(kB, nit);
      ATTN_STEP(kA, vC, it);
      if (nit > qt) break;
      it = nit;
      nit = it + 4;
      LOADV(vC, it);
      if (nit <= qt) LOADK(kA, nit);
      ATTN_STEP(kB, vC, it);
      if (nit > qt) break;
      it = nit;
    }
  }
  // per-half partial l -> full l (was per-step shfl_xor; now once)
  lval = xhalf_sum(lval);

  // merge 4 partials: waves 1-3 publish (m,l,O) to LDS; wave 0 combines.
  if (wv) {
    if (hi == 0) { Ms[wv][l32] = mval; Ls[wv][l32] = lval; }
#pragma unroll
    for (int dt = 0; dt < 4; dt++)
#pragma unroll
      for (int r = 0; r < 16; r++) {
        int d = dt * 32 + (r & 3) + 8 * (r >> 2) + 4 * hi;
        Om[wv - 1][d][l32] = oacc[dt][r];
      }
  }
  __syncthreads();
  if (wv == 0) {
    float m1 = Ms[1][l32], m2 = Ms[2][l32], m3 = Ms[3][l32];
    float l1 = Ls[1][l32], l2 = Ls[2][l32], l3 = Ls[3][l32];
    float mstar = fmaxf(fmaxf(mval, m1), fmaxf(m2, m3));
    float a0 = EXP2F(mval - mstar);
    float a1 = EXP2F(m1 - mstar);
    float a2 = EXP2F(m2 - mstar);
    float a3 = EXP2F(m3 - mstar);
    float linv = 1.f / (lval * a0 + l1 * a1 + l2 * a2 + l3 * a3);
    float* Og = Out + ((size_t)batch * T_ + qg) * D_;
#pragma unroll
    for (int dt = 0; dt < 4; dt++)
#pragma unroll
      for (int rg = 0; rg < 4; rg++) {
        int dbase = dt * 32 + 8 * rg + 4 * hi;
        float4 o;
#pragma unroll
        for (int c = 0; c < 4; c++) {
          float v = oacc[dt][rg * 4 + c] * a0 +
                    Om[0][dbase + c][l32] * a1 +
                    Om[1][dbase + c][l32] * a2 +
                    Om[2][dbase + c][l32] * a3;
          ((float*)&o)[c] = v * linv;
        }
        *(float4*)&Og[dbase] = o;
      }
  }
}

// ---------------------------------------------------------------------------
extern "C" void kernel_launch(void* const* d_in, const int* in_sizes, int n_in,
                              void* d_out, int out_size, void* d_ws, size_t ws_size,
                              hipStream_t stream) {
  const float* X  = (const float*)d_in[0];
  const float* Wq = (const float*)d_in[1];
  const float* Wk = (const float*)d_in[2];
  const float* Wv = (const float*)d_in[3];
  float* Out = (float*)d_out;

  char* ws = (char*)d_ws;
  unsigned short* Wf  = (unsigned short*)(ws);                        // 768 KB
  unsigned short* Qf  = (unsigned short*)(ws + 786432);               // 4 MB
  unsigned short* Kf  = (unsigned short*)(ws + 786432 + 4194304);     // 4 MB
  unsigned short* Vf  = (unsigned short*)(ws + 786432 + 2 * 4194304); // 4 MB

  hipLaunchKernelGGL(wtrans_kernel, dim3(96), dim3(256), 0, stream, Wq, Wk, Wv, Wf);
  hipLaunchKernelGGL(qkv_kernel, dim3(512), dim3(256), 0, stream, X, Wf, Qf, Kf, Vf);
  hipLaunchKernelGGL(attn_kernel, dim3(512), dim3(256), 0, stream, Qf, Kf, Vf, Out);
}